// Round 16
// baseline (1200.704 us; speedup 1.0000x reference)
//
#include <hip/hip_runtime.h>

#define NN 50000
#define EE 800000
#define NBIN 8192
#define RMAXT 17.33f

// ---------- bf16 helpers (RNE) ----------
__device__ __forceinline__ unsigned f2bf(float f){
  unsigned u = __float_as_uint(f);
  return (u + 0x7fffu + ((u>>16)&1u)) >> 16;
}
__device__ __forceinline__ float bf2f(unsigned hs){ return __uint_as_float(hs<<16); }
__device__ __forceinline__ unsigned pk2(float a, float b){ return f2bf(a) | (f2bf(b)<<16); }
__device__ __forceinline__ float gx(const unsigned* __restrict__ B, int base, int c){
  unsigned u = B[base + (c>>1)];
  return bf2f((c&1)? (u>>16) : (u&0xffffu));
}
__device__ __forceinline__ float gq(const unsigned* __restrict__ Q, int c){
  unsigned u = Q[4 + (c>>1)];
  return bf2f((c&1)? (u>>16) : (u&0xffffu));
}

// radial MLP (exact) — used only by the LUT builder
__device__ __forceinline__ void radial_mlp(const float* __restrict__ W1,
                                           const float* __restrict__ b1,
                                           const float* __restrict__ W2,
                                           const float* __restrict__ b2,
                                           const float* basis, float* rk){
#pragma unroll
  for(int p=0;p<5;p++) rk[p]=b2[p];
  for(int h=0;h<64;h++){
    float t=b1[h];
#pragma unroll
    for(int b=0;b<16;b++) t += basis[b]*W1[b*64+h];
    float sg = t/(1.f+__expf(-t));
#pragma unroll
    for(int p=0;p<5;p++) rk[p]+=sg*W2[h*5+p];
  }
}

// ---------- radial LUT ----------
__global__ __launch_bounds__(256) void k_lut(
  const float* __restrict__ W1k, const float* __restrict__ b1k,
  const float* __restrict__ W2k, const float* __restrict__ b2k,
  const float* __restrict__ W1v, const float* __restrict__ b1v,
  const float* __restrict__ W2v, const float* __restrict__ b2v,
  float* __restrict__ RT)
{
  int idx = blockIdx.x*256 + threadIdx.x;
  if(idx >= 2*NBIN) return;
  int l = idx / NBIN, bin = idx % NBIN;
  float r = (float)bin * (RMAXT/(float)(NBIN-1));
  float basis[16];
#pragma unroll
  for(int b=0;b<16;b++){
    float d=(r - (10.f/15.f)*(float)b)*1.6f;
    basis[b]=__expf(-d*d);
  }
  float rk[5], rv[5];
  radial_mlp(W1k+l*1024, b1k+l*64, W2k+l*320, b2k+l*5, basis, rk);
  radial_mlp(W1v+l*1024, b1v+l*64, W2v+l*320, b2v+l*5, basis, rv);
  float* row = RT + ((size_t)l*NBIN + bin)*16;
#pragma unroll
  for(int p=0;p<5;p++) row[p]=rk[p];
#pragma unroll
  for(int p=0;p<5;p++) row[5+p]=rv[p];
  row[10]=0.f; row[11]=0.f;
}

// ---------- CSR build ----------
__global__ __launch_bounds__(256) void k_hist(const int* __restrict__ esrc, const int* __restrict__ edst,
                                              int* __restrict__ deg_s, int* __restrict__ deg_d){
  int e = blockIdx.x*256 + threadIdx.x;
  if(e<EE){ atomicAdd(&deg_s[esrc[e]],1); atomicAdd(&deg_d[edst[e]],1); }
}

__global__ __launch_bounds__(1024) void k_scan(const int* __restrict__ deg, int* __restrict__ rowptr){
  __shared__ int wsum[16];
  const int C = (NN + 1023)/1024;
  int t = threadIdx.x, lane = t&63, wid = t>>6;
  int lo = t*C, hi = lo+C; if(lo>NN) lo=NN; if(hi>NN) hi=NN;
  int loc = 0;
  for(int i=lo;i<hi;i++) loc += deg[i];
  int x = loc;
#pragma unroll
  for(int off=1; off<64; off<<=1){ int y = __shfl_up(x, off); if(lane>=off) x += y; }
  if(lane==63) wsum[wid] = x;
  __syncthreads();
  if(wid==0 && lane<16){
    int w = wsum[lane];
#pragma unroll
    for(int off=1; off<16; off<<=1){ int y = __shfl_up(w, off); if(lane>=off) w += y; }
    wsum[lane]=w;
  }
  __syncthreads();
  int base = (wid>0? wsum[wid-1]:0) + (x - loc);
  int run = base;
  for(int i=lo;i<hi;i++){ rowptr[i] = run; run += deg[i]; }
  if(t==1023) rowptr[NN] = run;
}

__global__ __launch_bounds__(256) void k_fill_src(const int* __restrict__ esrc, const int* __restrict__ edst,
                                                  const int* __restrict__ rp_s, int* __restrict__ cur_s,
                                                  int* __restrict__ esrc_s, int* __restrict__ edst_s){
  int e = blockIdx.x*256 + threadIdx.x;
  if(e>=EE) return;
  int s = esrc[e], d = edst[e];
  int q = rp_s[s] + atomicAdd(&cur_s[s],1);
  esrc_s[q]=s; edst_s[q]=d;
}
__global__ __launch_bounds__(256) void k_fill_dst(const int* __restrict__ edst_s,
                                                  const int* __restrict__ rp_d, int* __restrict__ cur_d,
                                                  int* __restrict__ eidq){
  int q = blockIdx.x*256 + threadIdx.x;
  if(q>=EE) return;
  int d = edst_s[q];
  int p = rp_d[d] + atomicAdd(&cur_d[d],1);
  eidq[p] = q;
}

// ---------- s = f @ W_in ----------
__global__ __launch_bounds__(256) void k_sinit(const float* __restrict__ f,
                                               const float* __restrict__ Win,
                                               float* __restrict__ s){
  int n = blockIdx.x*256 + threadIdx.x;
  if(n>=NN) return;
  float fi[32], acc[32];
  const float4* fp = reinterpret_cast<const float4*>(f + (size_t)n*32);
#pragma unroll
  for(int i=0;i<8;i++){ float4 t=fp[i]; fi[4*i]=t.x; fi[4*i+1]=t.y; fi[4*i+2]=t.z; fi[4*i+3]=t.w; }
#pragma unroll
  for(int j=0;j<32;j++) acc[j]=0.f;
  for(int i=0;i<32;i++){
    float c=fi[i];
#pragma unroll
    for(int j=0;j<32;j++) acc[j]+=c*Win[i*32+j];
  }
  float4* sp = reinterpret_cast<float4*>(s + (size_t)n*32);
#pragma unroll
  for(int i=0;i<8;i++){ float4 t; t.x=acc[4*i]; t.y=acc[4*i+1]; t.z=acc[4*i+2]; t.w=acc[4*i+3]; sp[i]=t; }
}

// ---------- per-node precompute: 4-wave role split + LDS weights ----------
#define LW_QS   0
#define LW_QV   1024
#define LW_KSS  1280
#define LW_KSV  2304
#define LW_KVS  2816
#define LW_KVVS 3072
#define LW_KVVV 3584
#define LW_VSS  3840
#define LW_VSV  4864
#define LW_VVS  5376
#define LW_VVVS 5632
#define LW_VVVV 6144

__device__ __forceinline__ void smat_pack(const float* __restrict__ Wl, const float* sn,
                                          unsigned* __restrict__ dst, int ncol){
  for(int j0=0;j0<ncol;j0+=8){
    float acc[8];
#pragma unroll
    for(int k=0;k<8;k++) acc[k]=0.f;
    for(int i=0;i<32;i++){
      float c=sn[i];
#pragma unroll
      for(int k=0;k<8;k++) acc[k]+=c*Wl[i*ncol+j0+k];
    }
    uint4 u; u.x=pk2(acc[0],acc[1]); u.y=pk2(acc[2],acc[3]);
    u.z=pk2(acc[4],acc[5]); u.w=pk2(acc[6],acc[7]);
    reinterpret_cast<uint4*>(dst)[j0>>3]=u;
  }
}
__device__ __forceinline__ void vmat16_pack(const float* __restrict__ Wl, const float* vn,
                                            unsigned* __restrict__ dst, int stride, int w0){
  float a48[48];
  for(int w=0;w<16;w++){
    float ax=0.f,ay=0.f,az=0.f;
#pragma unroll
    for(int t=0;t<16;t++){
      float wt=Wl[t*stride+w0+w];
      ax+=vn[t*3]*wt; ay+=vn[t*3+1]*wt; az+=vn[t*3+2]*wt;
    }
    a48[w*3]=ax; a48[w*3+1]=ay; a48[w*3+2]=az;
  }
#pragma unroll
  for(int k=0;k<6;k++){
    uint4 u; u.x=pk2(a48[8*k],a48[8*k+1]); u.y=pk2(a48[8*k+2],a48[8*k+3]);
    u.z=pk2(a48[8*k+4],a48[8*k+5]); u.w=pk2(a48[8*k+6],a48[8*k+7]);
    reinterpret_cast<uint4*>(dst)[k]=u;
  }
}

__global__ __launch_bounds__(256) void k_nodeprep(
  const float* __restrict__ s, const float* __restrict__ v, const float* __restrict__ pos,
  const float* __restrict__ Wqs, const float* __restrict__ Wqv,
  const float* __restrict__ Kss, const float* __restrict__ Ksv, const float* __restrict__ Kvs,
  const float* __restrict__ Kvvs, const float* __restrict__ Kvvv,
  const float* __restrict__ Vss, const float* __restrict__ Vsv, const float* __restrict__ Vvs,
  const float* __restrict__ Vvvs, const float* __restrict__ Vvvv,
  unsigned* __restrict__ QPh, unsigned* __restrict__ SPh)
{
  __shared__ float WL[6400];
  int tid=threadIdx.x;
  for(int i=tid;i<1024;i+=256) WL[LW_QS +i]=Wqs[i];
  for(int i=tid;i<256; i+=256) WL[LW_QV +i]=Wqv[i];
  for(int i=tid;i<1024;i+=256) WL[LW_KSS+i]=Kss[i];
  for(int i=tid;i<512; i+=256) WL[LW_KSV+i]=Ksv[i];
  for(int i=tid;i<256; i+=256) WL[LW_KVS+i]=Kvs[i];
  for(int i=tid;i<512; i+=256) WL[LW_KVVS+i]=Kvvs[i];
  for(int i=tid;i<256; i+=256) WL[LW_KVVV+i]=Kvvv[i];
  for(int i=tid;i<1024;i+=256) WL[LW_VSS+i]=Vss[i];
  for(int i=tid;i<512; i+=256) WL[LW_VSV+i]=Vsv[i];
  for(int i=tid;i<256; i+=256) WL[LW_VVS+i]=Vvs[i];
  for(int i=tid;i<512; i+=256) WL[LW_VVVS+i]=Vvvs[i];
  for(int i=tid;i<256; i+=256) WL[LW_VVVV+i]=Vvvv[i];
  __syncthreads();

  int wid=tid>>6, lane=tid&63;
  int n = blockIdx.x*64 + lane;
  if(n>=NN) return;
  unsigned* qrow = QPh + (size_t)n*64;
  unsigned* brow = SPh + (size_t)n*256;

  if(wid<2){
    float sn[32];
    const float4* sp=reinterpret_cast<const float4*>(s+(size_t)n*32);
#pragma unroll
    for(int i=0;i<8;i++){ float4 t=sp[i]; sn[4*i]=t.x; sn[4*i+1]=t.y; sn[4*i+2]=t.z; sn[4*i+3]=t.w; }
    if(wid==0){
      smat_pack(WL+LW_QS,  sn, qrow+4, 32);
      smat_pack(WL+LW_KSS, sn, brow,   32);
      qrow[0]=__float_as_uint(pos[(size_t)n*3]);
      qrow[1]=__float_as_uint(pos[(size_t)n*3+1]);
      qrow[2]=__float_as_uint(pos[(size_t)n*3+2]);
      qrow[3]=0u;
    }else{
      smat_pack(WL+LW_VSS, sn, brow+120, 32);
      smat_pack(WL+LW_KSV, sn, brow+16,  16);
      smat_pack(WL+LW_VSV, sn, brow+136, 16);
      float vn[48];
      const float4* vp=reinterpret_cast<const float4*>(v+(size_t)n*48);
#pragma unroll
      for(int i=0;i<12;i++){ float4 t=vp[i]; vn[4*i]=t.x; vn[4*i+1]=t.y; vn[4*i+2]=t.z; vn[4*i+3]=t.w; }
      vmat16_pack(WL+LW_QV, vn, qrow+20, 16, 0);
      brow[240]=__float_as_uint(pos[(size_t)n*3]);
      brow[241]=__float_as_uint(pos[(size_t)n*3+1]);
      brow[242]=__float_as_uint(pos[(size_t)n*3+2]);
    }
  }else{
    float vn[48];
    const float4* vp=reinterpret_cast<const float4*>(v+(size_t)n*48);
#pragma unroll
    for(int i=0;i<12;i++){ float4 t=vp[i]; vn[4*i]=t.x; vn[4*i+1]=t.y; vn[4*i+2]=t.z; vn[4*i+3]=t.w; }
    if(wid==2){
      vmat16_pack(WL+LW_KVS,  vn, brow+24,    16, 0);
      vmat16_pack(WL+LW_KVVS, vn, brow+48,    32, 0);
      vmat16_pack(WL+LW_KVVS, vn, brow+48+24, 32, 16);
      vmat16_pack(WL+LW_KVVV, vn, brow+96,    16, 0);
    }else{
      vmat16_pack(WL+LW_VVS,  vn, brow+144,     16, 0);
      vmat16_pack(WL+LW_VVVS, vn, brow+168,     32, 0);
      vmat16_pack(WL+LW_VVVS, vn, brow+168+24,  32, 16);
      vmat16_pack(WL+LW_VVVV, vn, brow+216,     16, 0);
    }
  }
}

// ---------- fused edge pass (src-sorted): LUT radial + logit + bf16 message ----------
__global__ __launch_bounds__(256) void k_edge(
  const int* __restrict__ esrc_s, const int* __restrict__ edst_s,
  const float* __restrict__ RT,
  const unsigned* __restrict__ QPh, const unsigned* __restrict__ SPh,
  float* __restrict__ logit, unsigned* __restrict__ rec)
{
  int q = blockIdx.x*256 + threadIdx.x;
  if(q>=EE) return;
  int src=esrc_s[q], dst=edst_s[q];
  const unsigned* B = SPh + (size_t)src*256;
  const unsigned* Q = QPh + (size_t)dst*64;
  float px = __uint_as_float(B[240]) - __uint_as_float(Q[0]);
  float py = __uint_as_float(B[241]) - __uint_as_float(Q[1]);
  float pz = __uint_as_float(B[242]) - __uint_as_float(Q[2]);
  float r = sqrtf(px*px+py*py+pz*pz);
  float inv = 1.f/(r+1e-9f);
  float yx=px*inv, yy=py*inv, yz=pz*inv;

  float u = r * ((float)(NBIN-1)/RMAXT);
  int i0 = (int)u; if(i0 > NBIN-2) i0 = NBIN-2;
  float fr = u - (float)i0; fr = fminf(fr, 1.f);
  const float4* T0 = reinterpret_cast<const float4*>(RT + (size_t)i0*16);
  const float4* T1 = reinterpret_cast<const float4*>(RT + (size_t)(i0+1)*16);
  float4 A0=T0[0], B0=T0[1], C0=T0[2];
  float4 A1=T1[0], B1=T1[1], C1=T1[2];
  float rk0=A0.x+fr*(A1.x-A0.x), rk1=A0.y+fr*(A1.y-A0.y);
  float rk2=A0.z+fr*(A1.z-A0.z), rk3=A0.w+fr*(A1.w-A0.w);
  float rk4=B0.x+fr*(B1.x-B0.x);
  float rv0=B0.y+fr*(B1.y-B0.y), rv1=B0.z+fr*(B1.z-B0.z);
  float rv2=B0.w+fr*(B1.w-B0.w);
  float rv3=C0.x+fr*(C1.x-C0.x), rv4=C0.y+fr*(C1.y-C0.y);

  float lg=0.f;
#pragma unroll
  for(int j=0;j<32;j++){
    float d = yx*gx(B,48,3*j)+yy*gx(B,48,3*j+1)+yz*gx(B,48,3*j+2);
    lg += gq(Q,j)*(rk0*gx(B,0,j) + rk3*d);
  }
#pragma unroll
  for(int w=0;w<16;w++){
    float ax=gx(B,96,3*w),ay=gx(B,96,3*w+1),az=gx(B,96,3*w+2);
    float cx=ay*yz-az*yy, cy=az*yx-ax*yz, cz=ax*yy-ay*yx;   // cross(PKvvv, y)
    float aw=rk1*gx(B,16,w);
    float kx=aw*yx + rk2*gx(B,24,3*w)   + rk4*cx;
    float ky=aw*yy + rk2*gx(B,24,3*w+1) + rk4*cy;
    float kz=aw*yz + rk2*gx(B,24,3*w+2) + rk4*cz;
    lg += gq(Q,32+3*w)*kx + gq(Q,32+3*w+1)*ky + gq(Q,32+3*w+2)*kz;
  }
  lg *= 0.11180339887498948f;   // (S+3V)^-0.5
  logit[q]=lg;

  uint4* rp = reinterpret_cast<uint4*>(rec + (size_t)q*40);
#pragma unroll
  for(int j2=0;j2<4;j2++){
    float m8[8];
#pragma unroll
    for(int k=0;k<8;k++){
      int j=8*j2+k;
      float d = yx*gx(B,168,3*j)+yy*gx(B,168,3*j+1)+yz*gx(B,168,3*j+2);
      m8[k] = rv0*gx(B,120,j) + rv3*d;
    }
    uint4 u2; u2.x=pk2(m8[0],m8[1]); u2.y=pk2(m8[2],m8[3]);
    u2.z=pk2(m8[4],m8[5]); u2.w=pk2(m8[6],m8[7]);
    rp[j2]=u2;
  }
  unsigned rb[24];
#pragma unroll
  for(int w2=0;w2<8;w2++){
    float mm[6];
#pragma unroll
    for(int k=0;k<2;k++){
      int ww=2*w2+k;
      float ax=gx(B,216,3*ww),ay=gx(B,216,3*ww+1),az=gx(B,216,3*ww+2);
      float cx=ay*yz-az*yy, cy=az*yx-ax*yz, cz=ax*yy-ay*yx;   // cross(PVvvv, y)
      float aw=rv1*gx(B,136,ww);
      mm[3*k+0]=aw*yx + rv2*gx(B,144,3*ww)   + rv4*cx;
      mm[3*k+1]=aw*yy + rv2*gx(B,144,3*ww+1) + rv4*cy;
      mm[3*k+2]=aw*yz + rv2*gx(B,144,3*ww+2) + rv4*cz;
    }
    rb[3*w2]  =pk2(mm[0],mm[1]);
    rb[3*w2+1]=pk2(mm[2],mm[3]);
    rb[3*w2+2]=pk2(mm[4],mm[5]);
  }
#pragma unroll
  for(int k=0;k<6;k++){
    uint4 u2; u2.x=rb[4*k]; u2.y=rb[4*k+1]; u2.z=rb[4*k+2]; u2.w=rb[4*k+3];
    rp[4+k]=u2;
  }
}

// ---------- gather: wave-per-node, chunk max + 4-deep shfl-broadcast accumulate ----------
__global__ __launch_bounds__(256) void k_gather(
  const int* __restrict__ rp_d, const int* __restrict__ eidq,
  const float* __restrict__ logit, const unsigned* __restrict__ rec,
  float* __restrict__ s, float* __restrict__ v)
{
  int wid = threadIdx.x>>6, lane = threadIdx.x&63;
  int n = blockIdx.x*4 + wid;
  if(n>=NN) return;
  int i0=rp_d[n], i1=rp_d[n+1];
  bool act = lane<40;
  float mx=-3.4e38f, z=0.f, aX=0.f, aY=0.f;
  for(int base=i0; base<i1; base+=64){
    int cnt = i1-base; if(cnt>64) cnt=64;
    int q = 0; float lg = -3.4e38f;
    if(lane<cnt){ q = eidq[base+lane]; lg = logit[q]; }
    float cm = lg;
#pragma unroll
    for(int off=32; off; off>>=1) cm = fmaxf(cm, __shfl_xor(cm, off));
    if(cm > mx){
      float sc = __expf(mx - cm);
      z*=sc; aX*=sc; aY*=sc; mx=cm;
    }
    float a = (lane<cnt)? __expf(lg - mx) : 0.f;
    int i=0;
    for(; i+4<=cnt; i+=4){
      int q0=__shfl(q,i), q1=__shfl(q,i+1), q2=__shfl(q,i+2), q3=__shfl(q,i+3);
      float a0=__shfl(a,i), a1=__shfl(a,i+1), a2=__shfl(a,i+2), a3=__shfl(a,i+3);
      unsigned c0 = act? rec[(size_t)q0*40+lane] : 0u;
      unsigned c1 = act? rec[(size_t)q1*40+lane] : 0u;
      unsigned c2 = act? rec[(size_t)q2*40+lane] : 0u;
      unsigned c3 = act? rec[(size_t)q3*40+lane] : 0u;
      aX += a0*bf2f(c0&0xffffu) + a1*bf2f(c1&0xffffu) + a2*bf2f(c2&0xffffu) + a3*bf2f(c3&0xffffu);
      aY += a0*bf2f(c0>>16)     + a1*bf2f(c1>>16)     + a2*bf2f(c2>>16)     + a3*bf2f(c3>>16);
      z  += a0+a1+a2+a3;
    }
    for(; i<cnt; i++){
      int   qi = __shfl(q, i);
      float ai = __shfl(a, i);
      unsigned c = act? rec[(size_t)qi*40+lane] : 0u;
      aX += ai*bf2f(c&0xffffu);
      aY += ai*bf2f(c>>16);
      z  += ai;
    }
  }
  float zi = 1.f/(z+1e-9f);
  int c = lane*2;
  if(lane<16){
    float2* spp = reinterpret_cast<float2*>(s + (size_t)n*32 + c);
    float2 t = *spp; t.x += aX*zi; t.y += aY*zi; *spp = t;
  } else if(lane<40){
    float2* vpp = reinterpret_cast<float2*>(v + (size_t)n*48 + (c-32));
    float2 t = *vpp; t.x += aX*zi; t.y += aY*zi; *vpp = t;
  }
}

// ---------- readout: FCTP, output-split across gridDim.y=2, half-weights in LDS ----------
// block by owns os[8by..8by+8) and ov outputs o in [4by..4by+4).
// LDS u32 layout (per-block half): sss 0..4096 (4/row), vvs 4096..5120 (4/row),
// svv 5120..6144 (2/row), vsv 6144..7168 (2/row), vvv 7168..7680 (2/row)
__global__ __launch_bounds__(256) void k_readout(
  const float* __restrict__ s, const float* __restrict__ v,
  const float* __restrict__ Wsss, const float* __restrict__ Wvvs,
  const float* __restrict__ Wsvv, const float* __restrict__ Wvsv, const float* __restrict__ Wvvv,
  float* __restrict__ out)
{
  __shared__ unsigned WL[7680];   // 30720 B
  int tid = threadIdx.x;
  int by  = blockIdx.y;
  int ob8 = by*8, ob4 = by*4;
  for(int i=tid;i<4096;i+=256){
    int row=i>>2, o2=i&3;
    const float* p = Wsss + (size_t)row*16 + ob8 + 2*o2;
    WL[i] = pk2(p[0], p[1]);
  }
  for(int i=tid;i<1024;i+=256){
    int row=i>>2, o2=i&3;
    const float* p = Wvvs + (size_t)row*16 + ob8 + 2*o2;
    WL[4096+i] = pk2(p[0], p[1]);
  }
  for(int i=tid;i<1024;i+=256){
    int row=i>>1, o2=i&1;
    const float* p = Wsvv + (size_t)row*8 + ob4 + 2*o2;
    WL[5120+i] = pk2(p[0], p[1]);
  }
  for(int i=tid;i<1024;i+=256){
    int row=i>>1, o2=i&1;
    const float* p = Wvsv + (size_t)row*8 + ob4 + 2*o2;
    WL[6144+i] = pk2(p[0], p[1]);
  }
  for(int i=tid;i<512;i+=256){
    int row=i>>1, o2=i&1;
    const float* p = Wvvv + (size_t)row*8 + ob4 + 2*o2;
    WL[7168+i] = pk2(p[0], p[1]);
  }
  __syncthreads();

  int n = blockIdx.x*256 + tid;
  if(n>=NN) return;
  float sn[32], vn[48];
  const float4* sp=reinterpret_cast<const float4*>(s+(size_t)n*32);
#pragma unroll
  for(int i=0;i<8;i++){ float4 t=sp[i]; sn[4*i]=t.x; sn[4*i+1]=t.y; sn[4*i+2]=t.z; sn[4*i+3]=t.w; }
  const float4* vp=reinterpret_cast<const float4*>(v+(size_t)n*48);
#pragma unroll
  for(int i=0;i<12;i++){ float4 t=vp[i]; vn[4*i]=t.x; vn[4*i+1]=t.y; vn[4*i+2]=t.z; vn[4*i+3]=t.w; }

  float os[8];
#pragma unroll
  for(int o=0;o<8;o++) os[o]=0.f;
  // sss
  for(int a=0;a<32;a++){
    float sa=sn[a];
    for(int t=0;t<32;t++){
      float st=sa*sn[t];
      const unsigned* w=WL+((a<<5)+t)*4;
#pragma unroll
      for(int o2=0;o2<4;o2++){
        unsigned u=w[o2];
        os[2*o2]  +=st*bf2f(u&0xffffu);
        os[2*o2+1]+=st*bf2f(u>>16);
      }
    }
  }
  // vvs
  for(int a=0;a<16;a++){
    float ax=vn[a*3],ay=vn[a*3+1],az=vn[a*3+2];
    for(int b=0;b<16;b++){
      float d=ax*vn[b*3]+ay*vn[b*3+1]+az*vn[b*3+2];
      const unsigned* w=WL+4096+((a<<4)+b)*4;
#pragma unroll
      for(int o2=0;o2<4;o2++){
        unsigned u=w[o2];
        os[2*o2]  +=d*bf2f(u&0xffffu);
        os[2*o2+1]+=d*bf2f(u>>16);
      }
    }
  }
  float ov[12];
#pragma unroll
  for(int t=0;t<12;t++) ov[t]=0.f;
  // svv: B[o]=sum_a s_a W[a][w][o], o local in [0,4)
  for(int w=0;w<16;w++){
    float B[4];
#pragma unroll
    for(int o=0;o<4;o++) B[o]=0.f;
    for(int a=0;a<32;a++){
      const unsigned* ww=WL+5120+((a<<4)+w)*2;
      float sa=sn[a];
#pragma unroll
      for(int o2=0;o2<2;o2++){
        unsigned u=ww[o2];
        B[2*o2]  +=sa*bf2f(u&0xffffu);
        B[2*o2+1]+=sa*bf2f(u>>16);
      }
    }
#pragma unroll
    for(int o=0;o<4;o++){ float b=B[o]; ov[o*3]+=b*vn[w*3]; ov[o*3+1]+=b*vn[w*3+1]; ov[o*3+2]+=b*vn[w*3+2]; }
  }
  // vsv
  for(int vv=0;vv<16;vv++){
    float B[4];
#pragma unroll
    for(int o=0;o<4;o++) B[o]=0.f;
    for(int a=0;a<32;a++){
      const unsigned* ww=WL+6144+((vv<<5)+a)*2;
      float sa=sn[a];
#pragma unroll
      for(int o2=0;o2<2;o2++){
        unsigned u=ww[o2];
        B[2*o2]  +=sa*bf2f(u&0xffffu);
        B[2*o2+1]+=sa*bf2f(u>>16);
      }
    }
#pragma unroll
    for(int o=0;o<4;o++){ float b=B[o]; ov[o*3]+=b*vn[vv*3]; ov[o*3+1]+=b*vn[vv*3+1]; ov[o*3+2]+=b*vn[vv*3+2]; }
  }
  // vvv
  for(int a=0;a<16;a++){
    float ax=vn[a*3],ay=vn[a*3+1],az=vn[a*3+2];
    for(int b=0;b<16;b++){
      float bx=vn[b*3],by2=vn[b*3+1],bz=vn[b*3+2];
      float cx=ay*bz-az*by2, cy=az*bx-ax*bz, cz=ax*by2-ay*bx;
      const unsigned* w=WL+7168+((a<<4)+b)*2;
#pragma unroll
      for(int o2=0;o2<2;o2++){
        unsigned u=w[o2];
        float w0=bf2f(u&0xffffu), w1=bf2f(u>>16);
        int oa=2*o2, ob=2*o2+1;
        ov[oa*3]+=cx*w0; ov[oa*3+1]+=cy*w0; ov[oa*3+2]+=cz*w0;
        ov[ob*3]+=cx*w1; ov[ob*3+1]+=cy*w1; ov[ob*3+2]+=cz*w1;
      }
    }
  }
  float* op = out + (size_t)n*40;
#pragma unroll
  for(int o=0;o<8;o++) op[ob8+o]=os[o];
#pragma unroll
  for(int t=0;t<12;t++) op[16+12*by+t]=ov[t];
}

// ---------- launch ----------
extern "C" void kernel_launch(void* const* d_in, const int* in_sizes, int n_in,
                              void* d_out, int out_size, void* d_ws, size_t ws_size,
                              hipStream_t stream) {
  const float* f      = (const float*)d_in[0];
  const float* pos    = (const float*)d_in[1];
  const float* W_in   = (const float*)d_in[2];
  const float* Wq_s   = (const float*)d_in[3];
  const float* Wq_v   = (const float*)d_in[4];
  const float* Wk_ss  = (const float*)d_in[5];
  const float* Wk_sv  = (const float*)d_in[6];
  const float* Wk_vs  = (const float*)d_in[7];
  const float* Wk_vvs = (const float*)d_in[8];
  const float* Wk_vvv = (const float*)d_in[9];
  const float* W1k    = (const float*)d_in[10];
  const float* b1k    = (const float*)d_in[11];
  const float* W2k    = (const float*)d_in[12];
  const float* b2k    = (const float*)d_in[13];
  const float* Wv_ss  = (const float*)d_in[14];
  const float* Wv_sv  = (const float*)d_in[15];
  const float* Wv_vs  = (const float*)d_in[16];
  const float* Wv_vvs = (const float*)d_in[17];
  const float* Wv_vvv = (const float*)d_in[18];
  const float* W1v    = (const float*)d_in[19];
  const float* b1v    = (const float*)d_in[20];
  const float* W2v    = (const float*)d_in[21];
  const float* b2v    = (const float*)d_in[22];
  const float* Wr_sss = (const float*)d_in[23];
  const float* Wr_vvs = (const float*)d_in[24];
  const float* Wr_svv = (const float*)d_in[25];
  const float* Wr_vsv = (const float*)d_in[26];
  const float* Wr_vvv = (const float*)d_in[27];
  const int* esrc     = (const int*)d_in[28];
  const int* edst     = (const int*)d_in[29];

  char* w = (char*)d_ws;
  size_t off=0;
  auto takeB=[&](size_t bytes){ char* p=w+off; off+=(bytes+255)&~(size_t)255; return p; };
  float*    s      = (float*)   takeB((size_t)NN*32*4);
  float*    v      = (float*)   takeB((size_t)NN*48*4);
  unsigned* QPh    = (unsigned*)takeB((size_t)NN*64*4);
  unsigned* SPh    = (unsigned*)takeB((size_t)NN*256*4);
  unsigned* rec    = (unsigned*)takeB((size_t)EE*40*4);
  float*    logit  = (float*)   takeB((size_t)EE*4);
  float*    RT     = (float*)   takeB((size_t)2*NBIN*16*4);
  int*      esrc_s = (int*)     takeB((size_t)EE*4);
  int*      edst_s = (int*)     takeB((size_t)EE*4);
  int*      eidq   = (int*)     takeB((size_t)EE*4);
  int*      degs   = (int*)     takeB((size_t)NN*4*4);
  int*      rp_s   = (int*)     takeB((size_t)(NN+1)*4);
  int*      rp_d   = (int*)     takeB((size_t)(NN+1)*4);
  int* deg_s=degs, *cur_s=degs+NN, *deg_d=degs+2*NN, *cur_d=degs+3*NN;

  const int NB_N = (NN+255)/256;
  const int NB_E = (EE+255)/256;

  // radial LUT for both layers
  k_lut<<<(2*NBIN+255)/256,256,0,stream>>>(W1k,b1k,W2k,b2k, W1v,b1v,W2v,b2v, RT);

  // CSR build
  hipMemsetAsync(degs, 0, (size_t)NN*4*4, stream);
  k_hist<<<NB_E,256,0,stream>>>(esrc, edst, deg_s, deg_d);
  k_scan<<<1,1024,0,stream>>>(deg_s, rp_s);
  k_scan<<<1,1024,0,stream>>>(deg_d, rp_d);
  k_fill_src<<<NB_E,256,0,stream>>>(esrc, edst, rp_s, cur_s, esrc_s, edst_s);
  k_fill_dst<<<NB_E,256,0,stream>>>(edst_s, rp_d, cur_d, eidq);

  hipMemsetAsync(v, 0, (size_t)NN*48*4, stream);
  k_sinit<<<NB_N,256,0,stream>>>(f, W_in, s);

  for(int l=0;l<2;l++){
    k_nodeprep<<<(NN+63)/64,256,0,stream>>>(s, v, pos,
      Wq_s+l*1024, Wq_v+l*256,
      Wk_ss+l*1024, Wk_sv+l*512, Wk_vs+l*256, Wk_vvs+l*512, Wk_vvv+l*256,
      Wv_ss+l*1024, Wv_sv+l*512, Wv_vs+l*256, Wv_vvs+l*512, Wv_vvv+l*256,
      QPh, SPh);
    k_edge<<<NB_E,256,0,stream>>>(esrc_s, edst_s, RT + (size_t)l*NBIN*16,
      QPh, SPh, logit, rec);
    k_gather<<<(NN+3)/4,256,0,stream>>>(rp_d, eidq, logit, rec, s, v);
  }

  dim3 rg(NB_N, 2);
  k_readout<<<rg,256,0,stream>>>(s, v, Wr_sss, Wr_vvs, Wr_svv, Wr_vsv, Wr_vvv,
                                 (float*)d_out);
}